// Round 12
// baseline (281.432 us; speedup 1.0000x reference)
//
#include <hip/hip_runtime.h>
#include <math.h>

#define B_ 4
#define N_ 2048
#define D_ 512
#define H_ 8
#define E_ 64

constexpr float EPS = 1e-6f;
constexpr float PADV = -2.0f;
// attention scale folded into q at proj time, in exp2 domain:
constexpr float SCL = 0.18033688011112043f;  // 0.125 * log2(e)

typedef __attribute__((ext_vector_type(8))) __bf16 bf16x8;
typedef __attribute__((ext_vector_type(4))) float f32x4;

__device__ inline unsigned short f2bf(float f) {
  unsigned u = __builtin_bit_cast(unsigned, f);
  u += 0x7fffu + ((u >> 16) & 1u);  // RNE
  return (unsigned short)(u >> 16);
}
__device__ inline float bf2f(unsigned short v) {
  unsigned u = ((unsigned)v) << 16;
  return __builtin_bit_cast(float, u);
}

// ------------------------------------------- weight transpose+cast (once/launch)
__global__ __launch_bounds__(256) void prep_kernel(
    const float* __restrict__ qp, const float* __restrict__ kp,
    const float* __restrict__ vp, const float* __restrict__ gp,
    const float* __restrict__ ow, ushort* __restrict__ wT,
    ushort* __restrict__ owT) {
  __shared__ float Ls[64][65];
  int t = threadIdx.x;
  const float* src;
  ushort* dst;
  int src_ld, r0, c0;
  if (blockIdx.x < 256) {
    int set = blockIdx.x >> 6, tile = blockIdx.x & 63;
    int h = tile >> 3, dt = tile & 7;
    const float* w = set == 0 ? qp : set == 1 ? kp : set == 2 ? vp : gp;
    src = w + (size_t)h * 512 * 64;
    src_ld = 64;
    r0 = dt * 64;
    c0 = 0;
    dst = wT + ((size_t)set * 512 + h * 64) * 512;  // [e][d]
  } else {
    int idx = blockIdx.x - 256;
    src = ow;
    src_ld = 512;
    r0 = (idx >> 3) * 64;
    c0 = (idx & 7) * 64;
    dst = owT;
  }
#pragma unroll
  for (int i = 0; i < 4; i++) {
    int id = t + i * 256;
    int r = id >> 4, c4 = (id & 15) * 4;
    float4 v = *(const float4*)(src + (size_t)(r0 + r) * src_ld + c0 + c4);
    Ls[r][c4] = v.x;
    Ls[r][c4 + 1] = v.y;
    Ls[r][c4 + 2] = v.z;
    Ls[r][c4 + 3] = v.w;
  }
  __syncthreads();
#pragma unroll
  for (int i = 0; i < 4; i++) {
    int id = t + i * 256;
    int c = id >> 4, r4 = (id & 15) * 4;
    ushort4 o;
    o.x = f2bf(Ls[r4][c]);
    o.y = f2bf(Ls[r4 + 1][c]);
    o.z = f2bf(Ls[r4 + 2][c]);
    o.w = f2bf(Ls[r4 + 3][c]);
    *(ushort4*)(dst + (size_t)(c0 + c) * 512 + r0 + r4) = o;
  }
}

// ---------------------------------------------------------------- LayerNorms
__global__ __launch_bounds__(256) void ln_bf16_kernel(
    const float* __restrict__ x, const float* __restrict__ gamma,
    const float* __restrict__ beta, ushort* __restrict__ out) {
  int row = blockIdx.x;
  const float* xr = x + (size_t)row * D_;
  int c0 = threadIdx.x, c1 = threadIdx.x + 256;
  float v0 = xr[c0], v1 = xr[c1];
  __shared__ float red[8];
  int lane = threadIdx.x & 63, wid = threadIdx.x >> 6;
  float s = v0 + v1;
  for (int o = 32; o > 0; o >>= 1) s += __shfl_down(s, o, 64);
  if (lane == 0) red[wid] = s;
  __syncthreads();
  float mean = (red[0] + red[1] + red[2] + red[3]) * (1.0f / D_);
  float d0 = v0 - mean, d1 = v1 - mean;
  float sq = d0 * d0 + d1 * d1;
  for (int o = 32; o > 0; o >>= 1) sq += __shfl_down(sq, o, 64);
  if (lane == 0) red[4 + wid] = sq;
  __syncthreads();
  float var = (red[4] + red[5] + red[6] + red[7]) * (1.0f / D_);
  float rstd = rsqrtf(var + EPS);
  ushort* orow = out + (size_t)row * D_;
  orow[c0] = f2bf(gamma[c0] * (d0 * rstd) + beta[c0]);
  orow[c1] = f2bf(gamma[c1] * (d1 * rstd) + beta[c1]);
}

__global__ __launch_bounds__(256) void ln_kernel(
    const float* __restrict__ x, const float* __restrict__ gamma,
    const float* __restrict__ beta, float* __restrict__ out) {
  int row = blockIdx.x;
  const float* xr = x + (size_t)row * D_;
  int c0 = threadIdx.x, c1 = threadIdx.x + 256;
  float v0 = xr[c0], v1 = xr[c1];
  __shared__ float red[8];
  int lane = threadIdx.x & 63, wid = threadIdx.x >> 6;
  float s = v0 + v1;
  for (int o = 32; o > 0; o >>= 1) s += __shfl_down(s, o, 64);
  if (lane == 0) red[wid] = s;
  __syncthreads();
  float mean = (red[0] + red[1] + red[2] + red[3]) * (1.0f / D_);
  float d0 = v0 - mean, d1 = v1 - mean;
  float sq = d0 * d0 + d1 * d1;
  for (int o = 32; o > 0; o >>= 1) sq += __shfl_down(sq, o, 64);
  if (lane == 0) red[4 + wid] = sq;
  __syncthreads();
  float var = (red[4] + red[5] + red[6] + red[7]) * (1.0f / D_);
  float rstd = rsqrtf(var + EPS);
  float* orow = out + (size_t)row * D_;
  orow[c0] = gamma[c0] * (d0 * rstd) + beta[c0];
  orow[c1] = gamma[c1] * (d1 * rstd) + beta[c1];
}

// ------------------------------------------------- MFMA QKV+gate projection
// B-fragments read DIRECTLY from global (weights L2-resident; moves load
// from the saturated LDS pipe to the idle vmem pipe). Only A staged in LDS.
// q output PRE-SCALED by SCL for exp2-domain softmax.
__global__ __launch_bounds__(256) void proj_kernel(
    const ushort* __restrict__ xbf, const ushort* __restrict__ wT,
    const float* __restrict__ rope_cos, const float* __restrict__ rope_sin,
    ushort* __restrict__ qo, ushort* __restrict__ ko,
    ushort* __restrict__ vTo, ushort* __restrict__ go) {
  int tileM = blockIdx.x;
  int h = blockIdx.y & 7;
  int set = blockIdx.y >> 3;

  __shared__ ushort As[128 * 64];

  const int t = threadIdx.x;
  const int w = t >> 6;
  const int lane = t & 63;
  const int quad = lane >> 4;
  const int n15 = lane & 15;

  const ushort* wbase = wT + ((size_t)set * 512 + h * 64) * 512;  // [e][d]
  const int bn0 = tileM * 128;

  f32x4 acc[2][4];
#pragma unroll
  for (int mb = 0; mb < 2; mb++)
#pragma unroll
    for (int tt = 0; tt < 4; tt++) acc[mb][tt] = (f32x4){0.f, 0.f, 0.f, 0.f};

  for (int k0 = 0; k0 < 512; k0 += 64) {
    __syncthreads();
#pragma unroll
    for (int i = 0; i < 4; i++) {
      int c = t + i * 256;
      int row = c >> 3, c8 = c & 7;
      *(uint4*)&As[(row << 6) + ((c8 ^ (row & 7)) << 3)] =
          *(const uint4*)(xbf + (size_t)(bn0 + row) * 512 + k0 + (c8 << 3));
    }
    __syncthreads();
#pragma unroll
    for (int kk = 0; kk < 2; kk++) {
      bf16x8 af[2], bfr[4];
#pragma unroll
      for (int mb = 0; mb < 2; mb++) {
        int m = 32 * w + 16 * mb + n15;
        af[mb] = __builtin_bit_cast(
            bf16x8,
            *(const uint4*)&As[(m << 6) + ((((kk << 2) + quad) ^ (m & 7)) << 3)]);
      }
#pragma unroll
      for (int tt = 0; tt < 4; tt++) {
        // direct global B-frag: col n = 16tt+n15, 8 consecutive k
        bfr[tt] = __builtin_bit_cast(
            bf16x8, *(const uint4*)(wbase + (size_t)(16 * tt + n15) * 512 +
                                    k0 + (((kk << 2) + quad) << 3)));
      }
#pragma unroll
      for (int mb = 0; mb < 2; mb++)
#pragma unroll
        for (int tt = 0; tt < 4; tt++)
          acc[mb][tt] = __builtin_amdgcn_mfma_f32_16x16x32_bf16(
              af[mb], bfr[tt], acc[mb][tt], 0, 0, 0);
    }
  }

  const int b = bn0 >> 11;
  const int n_base = bn0 & 2047;
  const int bh = b * H_ + h;
  const size_t bhN = (size_t)bh * N_;

  if (set <= 1) {
    ushort* dst = (set == 0) ? qo : ko;
    const float oscale = (set == 0) ? SCL : 1.0f;
    const float sgn = (n15 & 1) ? 1.f : -1.f;
#pragma unroll
    for (int tt = 0; tt < 4; tt++) {
      int e = 16 * tt + n15;
      float cv = rope_cos[(h << 6) + e];
      float sv = rope_sin[(h << 6) + e];
#pragma unroll
      for (int mb = 0; mb < 2; mb++) {
#pragma unroll
        for (int r = 0; r < 4; r++) {
          float xv = acc[mb][tt][r];
          float pv = __shfl_xor(xv, 1, 64);
          float ov = (xv * cv + sgn * pv * sv) * oscale;
          int n = n_base + 32 * w + 16 * mb + 4 * quad + r;
          dst[((bhN + n) << 6) + e] = f2bf(ov);
        }
      }
    }
  } else if (set == 2) {
#pragma unroll
    for (int tt = 0; tt < 4; tt++) {
      int e = 16 * tt + n15;
#pragma unroll
      for (int mb = 0; mb < 2; mb++) {
        int n0 = n_base + 32 * w + 16 * mb + 4 * quad;
        ushort4 pk;
        pk.x = f2bf(acc[mb][tt][0]);
        pk.y = f2bf(acc[mb][tt][1]);
        pk.z = f2bf(acc[mb][tt][2]);
        pk.w = f2bf(acc[mb][tt][3]);
        *(ushort4*)(vTo + ((size_t)(bh * 64 + e)) * N_ + n0) = pk;
      }
    }
  } else {
#pragma unroll
    for (int tt = 0; tt < 4; tt++) {
      int e = 16 * tt + n15;
#pragma unroll
      for (int mb = 0; mb < 2; mb++) {
#pragma unroll
        for (int r = 0; r < 4; r++) {
          int n = n_base + 32 * w + 16 * mb + 4 * quad + r;
          float sv = 1.0f / (1.0f + __expf(-acc[mb][tt][r]));
          go[((bhN + n) << 6) + e] = f2bf(sv);
        }
      }
    }
  }
}

// ------------------------------------------------------ MFMA flash attention
// (R8 version verbatim — 78 µs; mb=2 variants (R9/R11) regress on occupancy:
//  2048 waves = 8/CU = 25% cap vs R8's 4096 waves = 16/CU.)
__global__ __launch_bounds__(512, 4) void attn_kernel(
    const ushort* __restrict__ qb, const ushort* __restrict__ kb,
    const ushort* __restrict__ vT, const ushort* __restrict__ gb,
    const float* __restrict__ mask, ushort* __restrict__ out) {
  int qt = blockIdx.x;
  int bh = blockIdx.y;
  int b = bh >> 3, h = bh & 7;

  __shared__ uint Ksu[64 * 32];        // [key][e], xor-chunk swizzled
  __shared__ uint Vtsu[66 * 32];       // [e][key] rows 0..63; row 64 = ones
  __shared__ uint Pw[8 * 16 * 36];     // per-wave P [qrow][key], stride 36 uints
  __shared__ __align__(16) float kmb[64];  // key mask bias (0 / -1e9)

  const int t = threadIdx.x;
  const int w = t >> 6;
  const int lane = t & 63;
  const int quad = lane >> 4;
  const int n15 = lane & 15;
  const int sw = n15 & 7;

  const size_t bhN = (size_t)bh * N_;
  const size_t bN = (size_t)b * N_;
  const int q0 = qt * 128 + 16 * w;

  bf16x8 qf[2];
  {
    const ushort* qrow = qb + ((bhN + q0 + n15) << 6);
#pragma unroll
    for (int hf = 0; hf < 2; hf++)
      qf[hf] =
          __builtin_bit_cast(bf16x8, *(const uint4*)(qrow + 32 * hf + (quad << 3)));
  }

  if (t < 32) Vtsu[64 * 32 + t] = 0x3f803f80u;  // ones row (bf16 1.0 pairs)

  f32x4 O[4], O5;
  O5 = (f32x4){0.f, 0.f, 0.f, 0.f};
#pragma unroll
  for (int tt = 0; tt < 4; tt++) O[tt] = (f32x4){0.f, 0.f, 0.f, 0.f};

  uint* Pq = &Pw[w * 576];

  for (int m0 = 0; m0 < N_; m0 += 64) {
    __syncthreads();
    {
      int row = t >> 3, c8 = t & 7;
      int dst = row * 32 + ((c8 ^ (row & 7)) << 2);
      *(uint4*)&Ksu[dst] =
          *(const uint4*)(kb + ((bhN + m0 + row) << 6) + (c8 << 3));
      *(uint4*)&Vtsu[dst] =
          *(const uint4*)(vT + (size_t)(bh * 64 + row) * N_ + m0 + (c8 << 3));
    }
    if (t < 16) {
      f32x4 mv = *(const f32x4*)(mask + bN + m0 + 4 * t);
      f32x4 bias;
#pragma unroll
      for (int j = 0; j < 4; j++) bias[j] = (mv[j] == PADV) ? -1e9f : 0.f;
      *(f32x4*)&kmb[4 * t] = bias;
    }
    __syncthreads();

    f32x4 st[4];
#pragma unroll
    for (int tt = 0; tt < 4; tt++)
      st[tt] = *(const f32x4*)&kmb[16 * tt + 4 * quad];  // bias as C-init
#pragma unroll
    for (int hf = 0; hf < 2; hf++) {
#pragma unroll
      for (int tt = 0; tt < 4; tt++) {
        bf16x8 kf = __builtin_bit_cast(
            bf16x8, *(const uint4*)&Ksu[(16 * tt + n15) * 32 +
                                        (((quad + 4 * hf) ^ sw) << 2)]);
        st[tt] =
            __builtin_amdgcn_mfma_f32_16x16x32_bf16(kf, qf[hf], st[tt], 0, 0, 0);
      }
    }

    int rowb = n15 * 36;
#pragma unroll
    for (int tt = 0; tt < 4; tt++) {
      uint u0 = __builtin_bit_cast(
                    uint, __builtin_exp2f(fminf(st[tt][0], 60.f))) + 0x8000u;
      uint u1 = __builtin_bit_cast(
                    uint, __builtin_exp2f(fminf(st[tt][1], 60.f))) + 0x8000u;
      uint u2 = __builtin_bit_cast(
                    uint, __builtin_exp2f(fminf(st[tt][2], 60.f))) + 0x8000u;
      uint u3 = __builtin_bit_cast(
                    uint, __builtin_exp2f(fminf(st[tt][3], 60.f))) + 0x8000u;
      int a = rowb + ((2 * tt + (quad >> 1)) << 2) + ((quad & 1) << 1);
      Pq[a] = __builtin_amdgcn_perm(u1, u0, 0x07060302u);
      Pq[a + 1] = __builtin_amdgcn_perm(u3, u2, 0x07060302u);
    }
    __asm__ volatile("" ::: "memory");  // P writes ordered before reads (wave-private)

#pragma unroll
    for (int hf = 0; hf < 2; hf++) {
      bf16x8 pf = __builtin_bit_cast(
          bf16x8, *(const uint4*)&Pq[n15 * 36 + ((quad + 4 * hf) << 2)]);
      bf16x8 lf = __builtin_bit_cast(
          bf16x8, *(const uint4*)&Vtsu[64 * 32 + ((quad + 4 * hf) << 2)]);
      O5 = __builtin_amdgcn_mfma_f32_16x16x32_bf16(pf, lf, O5, 0, 0, 0);
#pragma unroll
      for (int tt = 0; tt < 4; tt++) {
        bf16x8 vf = __builtin_bit_cast(
            bf16x8, *(const uint4*)&Vtsu[(16 * tt + n15) * 32 +
                                         (((quad + 4 * hf) ^ sw) << 2)]);
        O[tt] =
            __builtin_amdgcn_mfma_f32_16x16x32_bf16(pf, vf, O[tt], 0, 0, 0);
      }
    }
  }

#pragma unroll
  for (int r = 0; r < 4; r++) {
    int n = q0 + 4 * quad + r;
    float qm = (mask[bN + n] == PADV) ? 0.f : 1.f;
    float inv = qm / fmaxf(O5[r], 1e-30f);
    const ushort* grow = gb + ((bhN + n) << 6);
    ushort* orow = out + ((bN + n) << 9) + (h << 6);
#pragma unroll
    for (int tt = 0; tt < 4; tt++) {
      int e = tt * 16 + n15;
      orow[e] = f2bf(O[tt][r] * inv * bf2f(grow[e]));
    }
  }
}

// ------------------------------------- MFMA out-proj + bias + residual
// B-fragments direct from global (owT L2-resident); only A staged in LDS.
__global__ __launch_bounds__(256) void outproj_kernel(
    const ushort* __restrict__ ain, const ushort* __restrict__ owT,
    const float* __restrict__ bias, const float* __restrict__ xres,
    float* __restrict__ out) {
  int tileM = blockIdx.x;
  int cc0 = blockIdx.y * 64;

  __shared__ ushort As[128 * 64];

  const int t = threadIdx.x;
  const int w = t >> 6;
  const int lane = t & 63;
  const int quad = lane >> 4;
  const int n15 = lane & 15;

  const ushort* wbase = owT + (size_t)cc0 * 512;  // [c][k]
  const int bn0 = tileM * 128;

  f32x4 acc[2][4];
#pragma unroll
  for (int mb = 0; mb < 2; mb++)
#pragma unroll
    for (int tt = 0; tt < 4; tt++) acc[mb][tt] = (f32x4){0.f, 0.f, 0.f, 0.f};

  for (int k0 = 0; k0 < 512; k0 += 64) {
    __syncthreads();
#pragma unroll
    for (int i = 0; i < 4; i++) {
      int c = t + i * 256;
      int row = c >> 3, c8 = c & 7;
      *(uint4*)&As[(row << 6) + ((c8 ^ (row & 7)) << 3)] =
          *(const uint4*)(ain + (size_t)(bn0 + row) * 512 + k0 + (c8 << 3));
    }
    __syncthreads();
#pragma unroll
    for (int kk = 0; kk < 2; kk++) {
      bf16x8 af[2], bfr[4];
#pragma unroll
      for (int mb = 0; mb < 2; mb++) {
        int m = 32 * w + 16 * mb + n15;
        af[mb] = __builtin_bit_cast(
            bf16x8,
            *(const uint4*)&As[(m << 6) + ((((kk << 2) + quad) ^ (m & 7)) << 3)]);
      }
#pragma unroll
      for (int tt = 0; tt < 4; tt++) {
        bfr[tt] = __builtin_bit_cast(
            bf16x8, *(const uint4*)(wbase + (size_t)(16 * tt + n15) * 512 +
                                    k0 + (((kk << 2) + quad) << 3)));
      }
#pragma unroll
      for (int mb = 0; mb < 2; mb++)
#pragma unroll
        for (int tt = 0; tt < 4; tt++)
          acc[mb][tt] = __builtin_amdgcn_mfma_f32_16x16x32_bf16(
              af[mb], bfr[tt], acc[mb][tt], 0, 0, 0);
    }
  }

#pragma unroll
  for (int tt = 0; tt < 4; tt++) {
    int c = cc0 + 16 * tt + n15;
    float bv = bias[c];
#pragma unroll
    for (int mb = 0; mb < 2; mb++) {
#pragma unroll
      for (int r = 0; r < 4; r++) {
        size_t row = bn0 + 32 * w + 16 * mb + 4 * quad + r;
        out[row * 512 + c] = acc[mb][tt][r] + bv + xres[row * 512 + c];
      }
    }
  }
}

extern "C" void kernel_launch(void* const* d_in, const int* in_sizes, int n_in,
                              void* d_out, int out_size, void* d_ws,
                              size_t ws_size, hipStream_t stream) {
  (void)in_sizes; (void)n_in; (void)out_size; (void)ws_size;
  const float* x = (const float*)d_in[0];
  const float* mask = (const float*)d_in[1];
  const float* q_proj = (const float*)d_in[2];
  const float* k_proj = (const float*)d_in[3];
  const float* v_proj = (const float*)d_in[4];
  const float* g = (const float*)d_in[5];
  const float* gamma_in = (const float*)d_in[6];
  const float* beta_in = (const float*)d_in[7];
  const float* gamma_out = (const float*)d_in[8];
  const float* beta_out = (const float*)d_in[9];
  const float* out_w = (const float*)d_in[10];
  const float* out_b = (const float*)d_in[11];
  const float* rope_cos = (const float*)d_in[12];
  const float* rope_sin = (const float*)d_in[13];

  char* p = (char*)d_ws;
  ushort* xbf   = (ushort*)p; p += (size_t)8 << 20;
  ushort* wT    = (ushort*)p; p += (size_t)2 << 20;
  ushort* owT   = (ushort*)p; p += (size_t)1 << 20;
  ushort* qb16  = (ushort*)p; p += (size_t)8 << 20;
  ushort* kb16  = (ushort*)p; p += (size_t)8 << 20;
  ushort* vT16  = (ushort*)p; p += (size_t)8 << 20;
  ushort* gate  = (ushort*)p; p += (size_t)8 << 20;
  ushort* attnb = (ushort*)p; p += (size_t)8 << 20;
  float* ypre   = (float*)p;  p += (size_t)16 << 20;

  prep_kernel<<<320, 256, 0, stream>>>(q_proj, k_proj, v_proj, g, out_w, wT,
                                       owT);

  ln_bf16_kernel<<<B_ * N_, 256, 0, stream>>>(x, gamma_in, beta_in, xbf);

  dim3 gp(64, 32);
  proj_kernel<<<gp, 256, 0, stream>>>(xbf, wT, rope_cos, rope_sin, qb16, kb16,
                                      vT16, gate);

  dim3 ga(16, 32);
  attn_kernel<<<ga, 512, 0, stream>>>(qb16, kb16, vT16, gate, mask, attnb);

  dim3 go(64, 8);
  outproj_kernel<<<go, 256, 0, stream>>>(attnb, owT, out_b, x, ypre);

  ln_kernel<<<B_ * N_, 256, 0, stream>>>(ypre, gamma_out, beta_out,
                                         (float*)d_out);
}

// Round 13
// 217.700 us; speedup vs baseline: 1.2928x; 1.2928x over previous
//
#include <hip/hip_runtime.h>
#include <math.h>

#define B_ 4
#define N_ 2048
#define D_ 512
#define H_ 8
#define E_ 64

constexpr float EPS = 1e-6f;
constexpr float PADV = -2.0f;
// attention scale folded into q at proj time, in exp2 domain:
constexpr float SCL = 0.18033688011112043f;  // 0.125 * log2(e)

typedef __attribute__((ext_vector_type(8))) __bf16 bf16x8;
typedef __attribute__((ext_vector_type(4))) float f32x4;

__device__ inline unsigned short f2bf(float f) {
  unsigned u = __builtin_bit_cast(unsigned, f);
  u += 0x7fffu + ((u >> 16) & 1u);  // RNE
  return (unsigned short)(u >> 16);
}
__device__ inline float bf2f(unsigned short v) {
  unsigned u = ((unsigned)v) << 16;
  return __builtin_bit_cast(float, u);
}

// ------------------------- fused LN(x)->bf16  +  weight transpose/cast
// blocks 0..8191: LayerNorm row -> bf16
// blocks 8192..8447: qkvg weight tiles w[h][d][e] -> wT[set][h][e][d]
// blocks 8448..8511: out_w [k][c] -> owT[c][k]
__global__ __launch_bounds__(256) void ln_prep_kernel(
    const float* __restrict__ x, const float* __restrict__ gamma,
    const float* __restrict__ beta, ushort* __restrict__ out,
    const float* __restrict__ qp, const float* __restrict__ kp,
    const float* __restrict__ vp, const float* __restrict__ gp,
    const float* __restrict__ ow, ushort* __restrict__ wT,
    ushort* __restrict__ owT) {
  int t = threadIdx.x;
  if (blockIdx.x < 8192) {
    int row = blockIdx.x;
    const float* xr = x + (size_t)row * D_;
    int c0 = t, c1 = t + 256;
    float v0 = xr[c0], v1 = xr[c1];
    __shared__ float red[8];
    int lane = t & 63, wid = t >> 6;
    float s = v0 + v1;
    for (int o = 32; o > 0; o >>= 1) s += __shfl_down(s, o, 64);
    if (lane == 0) red[wid] = s;
    __syncthreads();
    float mean = (red[0] + red[1] + red[2] + red[3]) * (1.0f / D_);
    float d0 = v0 - mean, d1 = v1 - mean;
    float sq = d0 * d0 + d1 * d1;
    for (int o = 32; o > 0; o >>= 1) sq += __shfl_down(sq, o, 64);
    if (lane == 0) red[4 + wid] = sq;
    __syncthreads();
    float var = (red[4] + red[5] + red[6] + red[7]) * (1.0f / D_);
    float rstd = rsqrtf(var + EPS);
    ushort* orow = out + (size_t)row * D_;
    orow[c0] = f2bf(gamma[c0] * (d0 * rstd) + beta[c0]);
    orow[c1] = f2bf(gamma[c1] * (d1 * rstd) + beta[c1]);
    return;
  }

  // ---- transpose path
  __shared__ float Ls[64][65];
  int bid = blockIdx.x - 8192;
  const float* src;
  ushort* dst;
  int src_ld, r0, c0;
  if (bid < 256) {
    int set = bid >> 6, tile = bid & 63;
    int h = tile >> 3, dt = tile & 7;
    const float* w = set == 0 ? qp : set == 1 ? kp : set == 2 ? vp : gp;
    src = w + (size_t)h * 512 * 64;
    src_ld = 64;
    r0 = dt * 64;
    c0 = 0;
    dst = wT + ((size_t)set * 512 + h * 64) * 512;  // [e][d]
  } else {
    int idx = bid - 256;
    src = ow;
    src_ld = 512;
    r0 = (idx >> 3) * 64;
    c0 = (idx & 7) * 64;
    dst = owT;
  }
#pragma unroll
  for (int i = 0; i < 4; i++) {
    int id = t + i * 256;
    int r = id >> 4, c4 = (id & 15) * 4;
    float4 v = *(const float4*)(src + (size_t)(r0 + r) * src_ld + c0 + c4);
    Ls[r][c4] = v.x;
    Ls[r][c4 + 1] = v.y;
    Ls[r][c4 + 2] = v.z;
    Ls[r][c4 + 3] = v.w;
  }
  __syncthreads();
#pragma unroll
  for (int i = 0; i < 4; i++) {
    int id = t + i * 256;
    int c = id >> 4, r4 = (id & 15) * 4;
    ushort4 o;
    o.x = f2bf(Ls[r4][c]);
    o.y = f2bf(Ls[r4 + 1][c]);
    o.z = f2bf(Ls[r4 + 2][c]);
    o.w = f2bf(Ls[r4 + 3][c]);
    *(ushort4*)(dst + (size_t)(c0 + c) * 512 + r0 + r4) = o;
  }
}

// ---------------------------------------------------------------- final LN
__global__ __launch_bounds__(256) void ln_kernel(
    const float* __restrict__ x, const float* __restrict__ gamma,
    const float* __restrict__ beta, float* __restrict__ out) {
  int row = blockIdx.x;
  const float* xr = x + (size_t)row * D_;
  int c0 = threadIdx.x, c1 = threadIdx.x + 256;
  float v0 = xr[c0], v1 = xr[c1];
  __shared__ float red[8];
  int lane = threadIdx.x & 63, wid = threadIdx.x >> 6;
  float s = v0 + v1;
  for (int o = 32; o > 0; o >>= 1) s += __shfl_down(s, o, 64);
  if (lane == 0) red[wid] = s;
  __syncthreads();
  float mean = (red[0] + red[1] + red[2] + red[3]) * (1.0f / D_);
  float d0 = v0 - mean, d1 = v1 - mean;
  float sq = d0 * d0 + d1 * d1;
  for (int o = 32; o > 0; o >>= 1) sq += __shfl_down(sq, o, 64);
  if (lane == 0) red[4 + wid] = sq;
  __syncthreads();
  float var = (red[4] + red[5] + red[6] + red[7]) * (1.0f / D_);
  float rstd = rsqrtf(var + EPS);
  float* orow = out + (size_t)row * D_;
  orow[c0] = gamma[c0] * (d0 * rstd) + beta[c0];
  orow[c1] = gamma[c1] * (d1 * rstd) + beta[c1];
}

// ------------------------------------------------- MFMA QKV+gate projection
// (R8 128x64 version — validated best. 128x128 and direct-global-B both
//  regressed: R10 grid-shrink, R12 uncoalesced 1024B-stride B reads.)
__global__ __launch_bounds__(256) void proj_kernel(
    const ushort* __restrict__ xbf, const ushort* __restrict__ wT,
    const float* __restrict__ rope_cos, const float* __restrict__ rope_sin,
    ushort* __restrict__ qo, ushort* __restrict__ ko,
    ushort* __restrict__ vTo, ushort* __restrict__ go) {
  int tileM = blockIdx.x;
  int h = blockIdx.y & 7;
  int set = blockIdx.y >> 3;

  __shared__ ushort As[128 * 64];
  __shared__ ushort Bs[64 * 64];

  const int t = threadIdx.x;
  const int w = t >> 6;
  const int lane = t & 63;
  const int quad = lane >> 4;
  const int n15 = lane & 15;

  const ushort* wbase = wT + ((size_t)set * 512 + h * 64) * 512;  // [e][d]
  const int bn0 = tileM * 128;

  f32x4 acc[2][4];
#pragma unroll
  for (int mb = 0; mb < 2; mb++)
#pragma unroll
    for (int tt = 0; tt < 4; tt++) acc[mb][tt] = (f32x4){0.f, 0.f, 0.f, 0.f};

  for (int k0 = 0; k0 < 512; k0 += 64) {
    __syncthreads();
#pragma unroll
    for (int i = 0; i < 4; i++) {
      int c = t + i * 256;
      int row = c >> 3, c8 = c & 7;
      *(uint4*)&As[(row << 6) + ((c8 ^ (row & 7)) << 3)] =
          *(const uint4*)(xbf + (size_t)(bn0 + row) * 512 + k0 + (c8 << 3));
    }
#pragma unroll
    for (int i = 0; i < 2; i++) {
      int c = t + i * 256;
      int row = c >> 3, c8 = c & 7;
      *(uint4*)&Bs[(row << 6) + ((c8 ^ (row & 7)) << 3)] =
          *(const uint4*)(wbase + (size_t)row * 512 + k0 + (c8 << 3));
    }
    __syncthreads();
#pragma unroll
    for (int kk = 0; kk < 2; kk++) {
      bf16x8 af[2], bfr[4];
#pragma unroll
      for (int mb = 0; mb < 2; mb++) {
        int m = 32 * w + 16 * mb + n15;
        af[mb] = __builtin_bit_cast(
            bf16x8,
            *(const uint4*)&As[(m << 6) + ((((kk << 2) + quad) ^ (m & 7)) << 3)]);
      }
#pragma unroll
      for (int tt = 0; tt < 4; tt++) {
        int n = 16 * tt + n15;
        bfr[tt] = __builtin_bit_cast(
            bf16x8,
            *(const uint4*)&Bs[(n << 6) + ((((kk << 2) + quad) ^ (n & 7)) << 3)]);
      }
#pragma unroll
      for (int mb = 0; mb < 2; mb++)
#pragma unroll
        for (int tt = 0; tt < 4; tt++)
          acc[mb][tt] = __builtin_amdgcn_mfma_f32_16x16x32_bf16(
              af[mb], bfr[tt], acc[mb][tt], 0, 0, 0);
    }
  }

  const int b = bn0 >> 11;
  const int n_base = bn0 & 2047;
  const int bh = b * H_ + h;
  const size_t bhN = (size_t)bh * N_;

  if (set <= 1) {
    ushort* dst = (set == 0) ? qo : ko;
    const float oscale = (set == 0) ? SCL : 1.0f;
    const float sgn = (n15 & 1) ? 1.f : -1.f;
#pragma unroll
    for (int tt = 0; tt < 4; tt++) {
      int e = 16 * tt + n15;
      float cv = rope_cos[(h << 6) + e];
      float sv = rope_sin[(h << 6) + e];
#pragma unroll
      for (int mb = 0; mb < 2; mb++) {
#pragma unroll
        for (int r = 0; r < 4; r++) {
          float xv = acc[mb][tt][r];
          float pv = __shfl_xor(xv, 1, 64);
          float ov = (xv * cv + sgn * pv * sv) * oscale;
          int n = n_base + 32 * w + 16 * mb + 4 * quad + r;
          dst[((bhN + n) << 6) + e] = f2bf(ov);
        }
      }
    }
  } else if (set == 2) {
#pragma unroll
    for (int tt = 0; tt < 4; tt++) {
      int e = 16 * tt + n15;
#pragma unroll
      for (int mb = 0; mb < 2; mb++) {
        int n0 = n_base + 32 * w + 16 * mb + 4 * quad;
        ushort4 pk;
        pk.x = f2bf(acc[mb][tt][0]);
        pk.y = f2bf(acc[mb][tt][1]);
        pk.z = f2bf(acc[mb][tt][2]);
        pk.w = f2bf(acc[mb][tt][3]);
        *(ushort4*)(vTo + ((size_t)(bh * 64 + e)) * N_ + n0) = pk;
      }
    }
  } else {
#pragma unroll
    for (int tt = 0; tt < 4; tt++) {
      int e = 16 * tt + n15;
#pragma unroll
      for (int mb = 0; mb < 2; mb++) {
#pragma unroll
        for (int r = 0; r < 4; r++) {
          int n = n_base + 32 * w + 16 * mb + 4 * quad + r;
          float sv = 1.0f / (1.0f + __expf(-acc[mb][tt][r]));
          go[((bhN + n) << 6) + e] = f2bf(sv);
        }
      }
    }
  }
}

// ------------------------------------------------------ MFMA flash attention
// (R8 version verbatim — 78 µs; mb=2 variants (R9/R11) regress on occupancy:
//  2048 waves = 8/CU = 25% cap vs R8's 4096 waves = 16/CU.)
__global__ __launch_bounds__(512, 4) void attn_kernel(
    const ushort* __restrict__ qb, const ushort* __restrict__ kb,
    const ushort* __restrict__ vT, const ushort* __restrict__ gb,
    const float* __restrict__ mask, ushort* __restrict__ out) {
  int qt = blockIdx.x;
  int bh = blockIdx.y;
  int b = bh >> 3, h = bh & 7;

  __shared__ uint Ksu[64 * 32];        // [key][e], xor-chunk swizzled
  __shared__ uint Vtsu[66 * 32];       // [e][key] rows 0..63; row 64 = ones
  __shared__ uint Pw[8 * 16 * 36];     // per-wave P [qrow][key], stride 36 uints
  __shared__ __align__(16) float kmb[64];  // key mask bias (0 / -1e9)

  const int t = threadIdx.x;
  const int w = t >> 6;
  const int lane = t & 63;
  const int quad = lane >> 4;
  const int n15 = lane & 15;
  const int sw = n15 & 7;

  const size_t bhN = (size_t)bh * N_;
  const size_t bN = (size_t)b * N_;
  const int q0 = qt * 128 + 16 * w;

  bf16x8 qf[2];
  {
    const ushort* qrow = qb + ((bhN + q0 + n15) << 6);
#pragma unroll
    for (int hf = 0; hf < 2; hf++)
      qf[hf] =
          __builtin_bit_cast(bf16x8, *(const uint4*)(qrow + 32 * hf + (quad << 3)));
  }

  if (t < 32) Vtsu[64 * 32 + t] = 0x3f803f80u;  // ones row (bf16 1.0 pairs)

  f32x4 O[4], O5;
  O5 = (f32x4){0.f, 0.f, 0.f, 0.f};
#pragma unroll
  for (int tt = 0; tt < 4; tt++) O[tt] = (f32x4){0.f, 0.f, 0.f, 0.f};

  uint* Pq = &Pw[w * 576];

  for (int m0 = 0; m0 < N_; m0 += 64) {
    __syncthreads();
    {
      int row = t >> 3, c8 = t & 7;
      int dst = row * 32 + ((c8 ^ (row & 7)) << 2);
      *(uint4*)&Ksu[dst] =
          *(const uint4*)(kb + ((bhN + m0 + row) << 6) + (c8 << 3));
      *(uint4*)&Vtsu[dst] =
          *(const uint4*)(vT + (size_t)(bh * 64 + row) * N_ + m0 + (c8 << 3));
    }
    if (t < 16) {
      f32x4 mv = *(const f32x4*)(mask + bN + m0 + 4 * t);
      f32x4 bias;
#pragma unroll
      for (int j = 0; j < 4; j++) bias[j] = (mv[j] == PADV) ? -1e9f : 0.f;
      *(f32x4*)&kmb[4 * t] = bias;
    }
    __syncthreads();

    f32x4 st[4];
#pragma unroll
    for (int tt = 0; tt < 4; tt++)
      st[tt] = *(const f32x4*)&kmb[16 * tt + 4 * quad];  // bias as C-init
#pragma unroll
    for (int hf = 0; hf < 2; hf++) {
#pragma unroll
      for (int tt = 0; tt < 4; tt++) {
        bf16x8 kf = __builtin_bit_cast(
            bf16x8, *(const uint4*)&Ksu[(16 * tt + n15) * 32 +
                                        (((quad + 4 * hf) ^ sw) << 2)]);
        st[tt] =
            __builtin_amdgcn_mfma_f32_16x16x32_bf16(kf, qf[hf], st[tt], 0, 0, 0);
      }
    }

    int rowb = n15 * 36;
#pragma unroll
    for (int tt = 0; tt < 4; tt++) {
      uint u0 = __builtin_bit_cast(
                    uint, __builtin_exp2f(fminf(st[tt][0], 60.f))) + 0x8000u;
      uint u1 = __builtin_bit_cast(
                    uint, __builtin_exp2f(fminf(st[tt][1], 60.f))) + 0x8000u;
      uint u2 = __builtin_bit_cast(
                    uint, __builtin_exp2f(fminf(st[tt][2], 60.f))) + 0x8000u;
      uint u3 = __builtin_bit_cast(
                    uint, __builtin_exp2f(fminf(st[tt][3], 60.f))) + 0x8000u;
      int a = rowb + ((2 * tt + (quad >> 1)) << 2) + ((quad & 1) << 1);
      Pq[a] = __builtin_amdgcn_perm(u1, u0, 0x07060302u);
      Pq[a + 1] = __builtin_amdgcn_perm(u3, u2, 0x07060302u);
    }
    __asm__ volatile("" ::: "memory");  // P writes ordered before reads (wave-private)

#pragma unroll
    for (int hf = 0; hf < 2; hf++) {
      bf16x8 pf = __builtin_bit_cast(
          bf16x8, *(const uint4*)&Pq[n15 * 36 + ((quad + 4 * hf) << 2)]);
      bf16x8 lf = __builtin_bit_cast(
          bf16x8, *(const uint4*)&Vtsu[64 * 32 + ((quad + 4 * hf) << 2)]);
      O5 = __builtin_amdgcn_mfma_f32_16x16x32_bf16(pf, lf, O5, 0, 0, 0);
#pragma unroll
      for (int tt = 0; tt < 4; tt++) {
        bf16x8 vf = __builtin_bit_cast(
            bf16x8, *(const uint4*)&Vtsu[(16 * tt + n15) * 32 +
                                         (((quad + 4 * hf) ^ sw) << 2)]);
        O[tt] =
            __builtin_amdgcn_mfma_f32_16x16x32_bf16(pf, vf, O[tt], 0, 0, 0);
      }
    }
  }

#pragma unroll
  for (int r = 0; r < 4; r++) {
    int n = q0 + 4 * quad + r;
    float qm = (mask[bN + n] == PADV) ? 0.f : 1.f;
    float inv = qm / fmaxf(O5[r], 1e-30f);
    const ushort* grow = gb + ((bhN + n) << 6);
    ushort* orow = out + ((bN + n) << 9) + (h << 6);
#pragma unroll
    for (int tt = 0; tt < 4; tt++) {
      int e = tt * 16 + n15;
      orow[e] = f2bf(O[tt][r] * inv * bf2f(grow[e]));
    }
  }
}

// ------------------------------------- MFMA out-proj + bias + residual
// (R8 128x64 version)
__global__ __launch_bounds__(256) void outproj_kernel(
    const ushort* __restrict__ ain, const ushort* __restrict__ owT,
    const float* __restrict__ bias, const float* __restrict__ xres,
    float* __restrict__ out) {
  int tileM = blockIdx.x;
  int cc0 = blockIdx.y * 64;

  __shared__ ushort As[128 * 64];
  __shared__ ushort Bs[64 * 64];

  const int t = threadIdx.x;
  const int w = t >> 6;
  const int lane = t & 63;
  const int quad = lane >> 4;
  const int n15 = lane & 15;

  const ushort* wbase = owT + (size_t)cc0 * 512;  // [c][k]
  const int bn0 = tileM * 128;

  f32x4 acc[2][4];
#pragma unroll
  for (int mb = 0; mb < 2; mb++)
#pragma unroll
    for (int tt = 0; tt < 4; tt++) acc[mb][tt] = (f32x4){0.f, 0.f, 0.f, 0.f};

  for (int k0 = 0; k0 < 512; k0 += 64) {
    __syncthreads();
#pragma unroll
    for (int i = 0; i < 4; i++) {
      int c = t + i * 256;
      int row = c >> 3, c8 = c & 7;
      *(uint4*)&As[(row << 6) + ((c8 ^ (row & 7)) << 3)] =
          *(const uint4*)(ain + (size_t)(bn0 + row) * 512 + k0 + (c8 << 3));
    }
#pragma unroll
    for (int i = 0; i < 2; i++) {
      int c = t + i * 256;
      int row = c >> 3, c8 = c & 7;
      *(uint4*)&Bs[(row << 6) + ((c8 ^ (row & 7)) << 3)] =
          *(const uint4*)(wbase + (size_t)row * 512 + k0 + (c8 << 3));
    }
    __syncthreads();
#pragma unroll
    for (int kk = 0; kk < 2; kk++) {
      bf16x8 af[2], bfr[4];
#pragma unroll
      for (int mb = 0; mb < 2; mb++) {
        int m = 32 * w + 16 * mb + n15;
        af[mb] = __builtin_bit_cast(
            bf16x8,
            *(const uint4*)&As[(m << 6) + ((((kk << 2) + quad) ^ (m & 7)) << 3)]);
      }
#pragma unroll
      for (int tt = 0; tt < 4; tt++) {
        int n = 16 * tt + n15;
        bfr[tt] = __builtin_bit_cast(
            bf16x8,
            *(const uint4*)&Bs[(n << 6) + ((((kk << 2) + quad) ^ (n & 7)) << 3)]);
      }
#pragma unroll
      for (int mb = 0; mb < 2; mb++)
#pragma unroll
        for (int tt = 0; tt < 4; tt++)
          acc[mb][tt] = __builtin_amdgcn_mfma_f32_16x16x32_bf16(
              af[mb], bfr[tt], acc[mb][tt], 0, 0, 0);
    }
  }

#pragma unroll
  for (int tt = 0; tt < 4; tt++) {
    int c = cc0 + 16 * tt + n15;
    float bv = bias[c];
#pragma unroll
    for (int mb = 0; mb < 2; mb++) {
#pragma unroll
      for (int r = 0; r < 4; r++) {
        size_t row = bn0 + 32 * w + 16 * mb + 4 * quad + r;
        out[row * 512 + c] = acc[mb][tt][r] + bv + xres[row * 512 + c];
      }
    }
  }
}

extern "C" void kernel_launch(void* const* d_in, const int* in_sizes, int n_in,
                              void* d_out, int out_size, void* d_ws,
                              size_t ws_size, hipStream_t stream) {
  (void)in_sizes; (void)n_in; (void)out_size; (void)ws_size;
  const float* x = (const float*)d_in[0];
  const float* mask = (const float*)d_in[1];
  const float* q_proj = (const float*)d_in[2];
  const float* k_proj = (const float*)d_in[3];
  const float* v_proj = (const float*)d_in[4];
  const float* g = (const float*)d_in[5];
  const float* gamma_in = (const float*)d_in[6];
  const float* beta_in = (const float*)d_in[7];
  const float* gamma_out = (const float*)d_in[8];
  const float* beta_out = (const float*)d_in[9];
  const float* out_w = (const float*)d_in[10];
  const float* out_b = (const float*)d_in[11];
  const float* rope_cos = (const float*)d_in[12];
  const float* rope_sin = (const float*)d_in[13];

  char* p = (char*)d_ws;
  ushort* xbf   = (ushort*)p; p += (size_t)8 << 20;
  ushort* wT    = (ushort*)p; p += (size_t)2 << 20;
  ushort* owT   = (ushort*)p; p += (size_t)1 << 20;
  ushort* qb16  = (ushort*)p; p += (size_t)8 << 20;
  ushort* kb16  = (ushort*)p; p += (size_t)8 << 20;
  ushort* vT16  = (ushort*)p; p += (size_t)8 << 20;
  ushort* gate  = (ushort*)p; p += (size_t)8 << 20;
  ushort* attnb = (ushort*)p; p += (size_t)8 << 20;
  float* ypre   = (float*)p;  p += (size_t)16 << 20;

  // fused: LN(x)->bf16 (blocks 0..8191) + weight transposes (8192..8511)
  ln_prep_kernel<<<8512, 256, 0, stream>>>(x, gamma_in, beta_in, xbf, q_proj,
                                           k_proj, v_proj, g, out_w, wT, owT);

  dim3 gp(64, 32);
  proj_kernel<<<gp, 256, 0, stream>>>(xbf, wT, rope_cos, rope_sin, qb16, kb16,
                                      vT16, gate);

  dim3 ga(16, 32);
  attn_kernel<<<ga, 512, 0, stream>>>(qb16, kb16, vT16, gate, mask, attnb);

  dim3 go(64, 8);
  outproj_kernel<<<go, 256, 0, stream>>>(attnb, owT, out_b, x, ypre);

  ln_kernel<<<B_ * N_, 256, 0, stream>>>(ypre, gamma_out, beta_out,
                                         (float*)d_out);
}